// Round 7
// baseline (310.392 us; speedup 1.0000x reference)
//
#include <hip/hip_runtime.h>
#include <hip/hip_bf16.h>
#include <math.h>

typedef __attribute__((ext_vector_type(8))) short short8v;
typedef __attribute__((ext_vector_type(4))) float float4v;

// ---------------- workspace layout (dword offsets) ----------------
static const size_t F_RAWP1B = 0;              // bf16 ch-last pooled raw conv1 [8192][144][12dw] = 14,155,776
static const size_t F_C2P    = 14155776;       // fp32 pooled raw conv2 [8192][800] = 6,553,600
static const size_t F_PART1  = 20709376;       // 8192*40
static const size_t F_PART2  = 21037056;       // 2048*100
static const size_t F_PART3  = 21241856;       // 256*20
static const size_t F_BN1    = 21246976;       // 40
static const size_t F_BN2    = 21247016;       // 100
static const size_t F_BN3    = 21247116;       // 20
static const size_t F_SRAW   = 21247136;       // 2560
static const size_t F_PINEW  = 21249696;       // 2560
static const size_t F_WB2    = 21252256;       // 19456 (76*64*8 bf16)
static const size_t F_WB1    = 21271712;       // 512   (32*32 bf16)
// overlays in rawp1b region (dead after conv2):
static const size_t F_HRAW   = 0;              // 8192*10
static const size_t F_MU     = 81920;          // 8192*256

__device__ __forceinline__ float relu_(float v) { return v > 0.f ? v : 0.f; }

__device__ __forceinline__ unsigned int pack_bf16x2(float a, float b) {
  __hip_bfloat16 ha = __float2bfloat16(a), hb = __float2bfloat16(b);
  unsigned short ua, ub;
  __builtin_memcpy(&ua, &ha, 2); __builtin_memcpy(&ub, &hb, 2);
  return ((unsigned int)ub << 16) | ua;
}

__device__ __forceinline__ float pick_(float a, float b, bool mx) {
  return mx ? fmaxf(a, b) : fminf(a, b);
}

// ---- conv1 weight prep: (20,1,5,5) -> wb1[n(32)][k(32)] bf16, k = kh*6+kw ----
__global__ __launch_bounds__(256) void k_wprep1(
    const float* __restrict__ w, unsigned short* __restrict__ wb1)
{
  const int i = blockIdx.x * 256 + threadIdx.x;   // 1024
  const int n = i >> 5, k = i & 31;
  const int kh = k / 6, kw = k - kh*6;
  float v = (n < 20 && kh < 5 && kw < 5) ? w[n*25 + kh*5 + kw] : 0.f;
  __hip_bfloat16 h = __float2bfloat16(v);
  unsigned short u; __builtin_memcpy(&u, &h, 2);
  wb1[i] = u;
}

// ---- conv2 weight prep: OIHW fp32 -> wb2[cc(76)][n(64)][j(8)] bf16 ----
__global__ __launch_bounds__(256) void k_wprep2(
    const float* __restrict__ w, unsigned short* __restrict__ wb)
{
  const int idx = blockIdx.x * 256 + threadIdx.x;    // 38912
  const int cc = idx >> 9;
  const int rem = idx & 511;
  const int n = rem >> 3, j = rem & 7;
  float v = 0.f;
  if (cc < 75 && n < 50) {
    const int khw = cc / 3, icg = cc - khw*3;
    const int ic = icg*8 + j;
    if (ic < 20) {
      const int kh = khw / 5, kw = khw - kh*5;
      v = w[((n*20 + ic)*5 + kh)*5 + kw];
    }
  }
  __hip_bfloat16 h = __float2bfloat16(v);
  unsigned short u; __builtin_memcpy(&u, &h, 2);
  wb[idx] = u;
}

// ---- conv1 MFMA implicit GEMM, packed-pair dual-copy LDS gather ----
// k-map: k = kh*6+kw. Pixel mapping verified R5/R6. In-lane 2x2 pool.
// Output: bf16 packed ch-last pooled raw [img][144][12dw] (48 B/pixel).
__global__ __launch_bounds__(256) void k_conv1_mfma(
    const float* __restrict__ x, const unsigned short* __restrict__ wb1,
    const float* __restrict__ g1, unsigned int* __restrict__ rawp1b,
    float* __restrict__ part)
{
  __shared__ alignas(16) unsigned short xpk[1568];   // [2 copies][28 rows][28 ushort]
  __shared__ float sred[4][32], qred[4][32];
  const int tid = threadIdx.x, img = blockIdx.x;
  const float* xp = x + (size_t)img * 784;
  for (int i = tid; i < 784; i += 256) {
    const int r = i / 28, c = i - r*28;
    __hip_bfloat16 h = __float2bfloat16(xp[i]);
    unsigned short u; __builtin_memcpy(&u, &h, 2);
    xpk[r*28 + c] = u;                         // copy0: pair cols (2d, 2d+1)
    if (c >= 1) xpk[784 + r*28 + (c-1)] = u;   // copy1: pair cols (1+2d, 2+2d)
    else        xpk[784 + r*28 + 27]  = 0;     // copy1 col-28 slot = 0
  }
  __syncthreads();
  const int wave = tid >> 6, lane = tid & 63, lo = lane & 15, hi = lane >> 4;

  const short8v bfr0 = *(const short8v*)(wb1 + (lo*32 + hi*8));
  const short8v bfr1 = *(const short8v*)(wb1 + ((16+lo)*32 + hi*8));

  // per-hi dword offsets (kh*14 + kw/2) for jj=0..3, byte-encoded
  const unsigned enc = (hi==0) ? 0x0E020100u
                     : (hi==1) ? 0x1D1C100Fu
                     : (hi==2) ? 0x2C2B2A1Eu
                     :           0x003A3938u;   // hi=3: jj3 = zero-weight dummy
  const int off0 = enc & 255, off1 = (enc>>8)&255, off2 = (enc>>16)&255, off3 = enc>>24;
  const unsigned int* xpd = (const unsigned int*)xpk;   // 784 dwords
  const int pb   = (lo & 1) * 392;
  const int oyp  = (lo >> 1) & 1, qoff = lo >> 2;
  const int inv  = pb + (6*wave + oyp)*14;

  float4v acc[9][2];
  #pragma unroll
  for (int t = 0; t < 9; ++t) {
    acc[t][0] = (float4v){0.f,0.f,0.f,0.f};
    acc[t][1] = (float4v){0.f,0.f,0.f,0.f};
  }

  #pragma unroll
  for (int tt = 0; tt < 9; ++tt) {
    // qoff<=3 never crosses a 12-pixel row: pyl/pxl are compile-time
    const int pylc = (tt*4) / 12;
    const int pxlc = (tt*4) - pylc*12;
    const int base = inv + pylc*28 + pxlc + qoff;
    union { unsigned int u[4]; short8v v; } cu;
    cu.u[0] = xpd[base + off0];
    cu.u[1] = xpd[base + off1];
    cu.u[2] = xpd[base + off2];
    cu.u[3] = xpd[base + off3];
    acc[tt][0] = __builtin_amdgcn_mfma_f32_16x16x32_bf16(cu.v, bfr0, acc[tt][0], 0, 0, 0);
    acc[tt][1] = __builtin_amdgcn_mfma_f32_16x16x32_bf16(cu.v, bfr1, acc[tt][1], 0, 0, 0);
  }

  // epilogue: stats (pre-pool) + in-lane sign-aware 2x2 pool + bf16 pack store
  const bool gp0 = (g1[lo] >= 0.f);
  const bool gp1 = (lo < 4) ? (g1[16+lo] >= 0.f) : true;
  float sv0 = 0.f, qv0 = 0.f, sv1 = 0.f, qv1 = 0.f;
  unsigned int* dst = rawp1b + (size_t)img * 1728;
  #pragma unroll
  for (int tt = 0; tt < 9; ++tt) {
    const int T = wave*9 + tt;
    const int q = T*4 + hi;
    const float4v v0 = acc[tt][0];
    const float4v v1 = acc[tt][1];
    #pragma unroll
    for (int r = 0; r < 4; ++r) { sv0 += v0[r]; qv0 += v0[r]*v0[r]; }
    #pragma unroll
    for (int r = 0; r < 4; ++r) { sv1 += v1[r]; qv1 += v1[r]*v1[r]; }
    const float p0 = pick_(pick_(v0[0], v0[1], gp0), pick_(v0[2], v0[3], gp0), gp0);
    const float p1 = pick_(pick_(v1[0], v1[1], gp1), pick_(v1[2], v1[3], gp1), gp1);
    const float o0 = __shfl_down(p0, 1);
    const float o1 = __shfl_down(p1, 1);
    if ((lo & 1) == 0) {
      dst[q*12 + (lo >> 1)] = pack_bf16x2(p0, o0);          // oc pair (lo, lo+1)
      if (lo < 8)
        dst[q*12 + 8 + (lo >> 1)] = pack_bf16x2(p1, o1);    // oc 16.. (pads=0)
    }
  }
  sv0 += __shfl_down(sv0, 32); qv0 += __shfl_down(qv0, 32);
  sv0 += __shfl_down(sv0, 16); qv0 += __shfl_down(qv0, 16);
  sv1 += __shfl_down(sv1, 32); qv1 += __shfl_down(qv1, 32);
  sv1 += __shfl_down(sv1, 16); qv1 += __shfl_down(qv1, 16);
  if (hi == 0) {
    sred[wave][lo] = sv0; sred[wave][16+lo] = sv1;
    qred[wave][lo] = qv0; qred[wave][16+lo] = qv1;
  }
  __syncthreads();
  if (tid < 20) {
    float s = 0.f, q = 0.f;
    #pragma unroll
    for (int w2 = 0; w2 < 4; ++w2) { s += sred[w2][tid]; q += qred[w2][tid]; }
    part[(size_t)img*40 + tid]      = s;
    part[(size_t)img*40 + 20 + tid] = q;
  }
}

// ---- conv2 implicit-GEMM MFMA, unrolled K-loop + LDS A-offset table;
//      uint4 staging applies BN1+ReLU via interleaved (sc,sh) table;
//      epilogue: BN2 partial stats + in-register sign-aware 2x2 pool ----
__global__ __launch_bounds__(256) void k_conv2_mfma(
    const unsigned int* __restrict__ rawp1b, const unsigned short* __restrict__ wb,
    const float* __restrict__ bn1, const float* __restrict__ g2,
    float* __restrict__ c2p, float* __restrict__ part)
{
  __shared__ alignas(16) unsigned int in4[6912];     // 4 imgs, bf16 ch-last [144][12dw]
  __shared__ float sred[4][64], qred[4][64];
  __shared__ alignas(16) float bn1i[48];             // (sc,sh) interleaved, ch 0..23
  __shared__ unsigned short aofft[76];               // A byte-offset per K-chunk
  const int tid = threadIdx.x, blk = blockIdx.x;
  if (tid < 24) {
    const float sc = (tid < 20) ? bn1[tid]      : 0.f;
    const float sh = (tid < 20) ? bn1[20 + tid] : 0.f;
    bn1i[2*tid] = sc; bn1i[2*tid + 1] = sh;
  }
  if (tid < 76) {
    const int cc2 = tid > 74 ? 74 : tid;             // chunk 75: weights are 0
    const int khw = cc2 / 3, icg = cc2 - khw*3;
    const int kh = khw / 5, kw = khw - kh*5;
    aofft[tid] = (unsigned short)((kh*12 + kw)*48 + icg*16);
  }
  __syncthreads();

  // staging: 1728 uint4, unpack bf16 pair -> BN1+ReLU -> repack
  const uint4* src4 = (const uint4*)(rawp1b + (size_t)blk * 6912);
  uint4* dst4 = (uint4*)in4;
  int jj = tid % 3;                                  // dword chp base = jj*4
  for (int k = 0; k < 7; ++k) {
    const int i = k*256 + tid;
    if (i < 1728) {
      const uint4 v = src4[i];
      unsigned int o[4];
      #pragma unroll
      for (int m = 0; m < 4; ++m) {
        const float4 ss = *(const float4*)(bn1i + jj*16 + m*4);
        const unsigned int u = (m==0) ? v.x : (m==1) ? v.y : (m==2) ? v.z : v.w;
        const float a = __uint_as_float(u << 16);
        const float b = __uint_as_float(u & 0xffff0000u);
        const float ra = relu_(fmaf(a, ss.x, ss.y));
        const float rb = relu_(fmaf(b, ss.z, ss.w));
        o[m] = pack_bf16x2(ra, rb);
      }
      uint4 ov; ov.x = o[0]; ov.y = o[1]; ov.z = o[2]; ov.w = o[3];
      dst4[i] = ov;
    }
    jj = (jj == 2) ? 0 : jj + 1;                     // 256 % 3 == 1
  }
  __syncthreads();

  const int wave = tid >> 6, lane = tid & 63;
  const int lo = lane & 15, hi = lane >> 4;
  const char* ibase = (const char*)in4 + wave * 6912;

  // per-lane A bases (pixel*48 bytes) and per-step A offsets from table
  const char* bA[4];
  #pragma unroll
  for (int a = 0; a < 4; ++a) {
    const int m = a*16 + lo;
    bA[a] = ibase + ((m >> 3) * 12 + (m & 7)) * 48;
  }
  unsigned short aoffs[19];
  #pragma unroll
  for (int s = 0; s < 19; ++s) aoffs[s] = aofft[s*4 + hi];
  const unsigned short* wbase = wb + hi*512 + lo*8;

  bool gpos[4];
  #pragma unroll
  for (int nf = 0; nf < 4; ++nf) {
    const int n = nf*16 + lo;
    gpos[nf] = (n < 50) ? (g2[n] >= 0.f) : true;
  }

  float4v acc[4][4];
  #pragma unroll
  for (int a = 0; a < 4; ++a)
    #pragma unroll
    for (int nf = 0; nf < 4; ++nf) acc[a][nf] = (float4v){0.f, 0.f, 0.f, 0.f};

  #pragma unroll
  for (int s = 0; s < 19; ++s) {
    short8v av[4], bv[4];
    #pragma unroll
    for (int am = 0; am < 4; ++am)
      av[am] = *(const short8v*)(bA[am] + aoffs[s]);
    const unsigned short* wrow = wbase + s*2048;     // (4s+hi)*512 + lo*8
    #pragma unroll
    for (int nf = 0; nf < 4; ++nf)
      bv[nf] = *(const short8v*)(wrow + nf*128);
    #pragma unroll
    for (int am = 0; am < 4; ++am)
      #pragma unroll
      for (int nf = 0; nf < 4; ++nf)
        acc[am][nf] = __builtin_amdgcn_mfma_f32_16x16x32_bf16(av[am], bv[nf], acc[am][nf], 0, 0, 0);
  }

  const int img = blk*4 + wave;
  #pragma unroll
  for (int nf = 0; nf < 4; ++nf) {
    const int n = nf*16 + lo;
    float sv = 0.f, qv = 0.f;
    #pragma unroll
    for (int am = 0; am < 4; ++am) {
      float4v v = acc[am][nf];
      #pragma unroll
      for (int r = 0; r < 4; ++r) { sv += v[r]; qv += v[r]*v[r]; }
      float h0 = gpos[nf] ? fmaxf(v[0], v[1]) : fminf(v[0], v[1]);
      float h1 = gpos[nf] ? fmaxf(v[2], v[3]) : fminf(v[2], v[3]);
      const float o0 = __shfl_xor(h0, 32);
      const float o1 = __shfl_xor(h1, 32);
      h0 = gpos[nf] ? fmaxf(h0, o0) : fminf(h0, o0);
      h1 = gpos[nf] ? fmaxf(h1, o1) : fminf(h1, o1);
      if (hi < 2 && n < 50) {
        float2 o; o.x = h0; o.y = h1;
        *(float2*)(c2p + (size_t)img*800 + n*16 + am*4 + hi*2) = o;
      }
    }
    sv += __shfl_down(sv, 32); qv += __shfl_down(qv, 32);
    sv += __shfl_down(sv, 16); qv += __shfl_down(qv, 16);
    if (hi == 0) { sred[wave][nf*16 + lo] = sv; qred[wave][nf*16 + lo] = qv; }
  }
  __syncthreads();
  if (tid < 100) {
    const int ch = tid < 50 ? tid : tid - 50;
    float t = 0.f;
    if (tid < 50) {
      #pragma unroll
      for (int w2 = 0; w2 < 4; ++w2) t += sred[w2][ch];
      part[(size_t)blk*100 + ch] = t;
    } else {
      #pragma unroll
      for (int w2 = 0; w2 < 4; ++w2) t += qred[w2][ch];
      part[(size_t)blk*100 + 50 + ch] = t;
    }
  }
}

// ---- BN finalize: reduce per-block partials (double), emit scale/shift ----
__global__ __launch_bounds__(256) void k_bn_fin(
    const float* __restrict__ part, int nblk, int nch, float N,
    const float* __restrict__ g, const float* __restrict__ b,
    float* __restrict__ out)
{
  __shared__ double rd[4][2];
  const int tid = threadIdx.x, ch = blockIdx.x;
  const int lane = tid & 63, wid = tid >> 6;
  double s = 0.0, q = 0.0;
  for (int i = tid; i < nblk; i += 256) {
    s += (double)part[(size_t)i*2*nch + ch];
    q += (double)part[(size_t)i*2*nch + nch + ch];
  }
  #pragma unroll
  for (int off = 32; off > 0; off >>= 1) { s += __shfl_down(s, off); q += __shfl_down(q, off); }
  if (lane == 0) { rd[wid][0] = s; rd[wid][1] = q; }
  __syncthreads();
  if (tid == 0) {
    double S = rd[0][0] + rd[1][0] + rd[2][0] + rd[3][0];
    double Q = rd[0][1] + rd[1][1] + rd[2][1] + rd[3][1];
    double mean = S / (double)N;
    double var  = Q / (double)N - mean * mean;
    if (var < 0.0) var = 0.0;
    float scv = (float)((double)g[ch] / sqrt(var + 1e-5));
    out[ch]       = scv;
    out[nch + ch] = b[ch] - (float)mean * scv;
  }
}

// ---- fc1 fused BN2+ReLU: 32 samples/block, 8-lane K-split ----
__global__ __launch_bounds__(256) void k_fc1(
    const float* __restrict__ c2p, const float* __restrict__ bn2,
    const float* __restrict__ fw, float* __restrict__ h_raw,
    float* __restrict__ part)
{
  __shared__ alignas(16) float wl[8000];
  __shared__ float s2[50], h2[50];
  __shared__ float red[4][20];
  const int tid = threadIdx.x;
  for (int i = tid; i < 2000; i += 256)
    ((float4*)wl)[i] = ((const float4*)fw)[i];
  if (tid < 50) { s2[tid] = bn2[tid]; h2[tid] = bn2[50 + tid]; }
  __syncthreads();
  const int s = tid >> 3, kc = tid & 7;
  const int sample = blockIdx.x * 32 + s;
  const float* xr = c2p + (size_t)sample * 800 + kc * 100;
  float acc[10];
  #pragma unroll
  for (int f = 0; f < 10; ++f) acc[f] = 0.f;
  #pragma unroll 5
  for (int c = 0; c < 25; ++c) {
    const int k = kc*100 + c*4;
    float4 v = *(const float4*)(xr + c*4);
    const int oc = k >> 4;
    const float sc = s2[oc], sh = h2[oc];
    v.x = relu_(v.x*sc + sh); v.y = relu_(v.y*sc + sh);
    v.z = relu_(v.z*sc + sh); v.w = relu_(v.w*sc + sh);
    #pragma unroll
    for (int f = 0; f < 10; ++f) {
      const float4 wv = *(const float4*)(wl + f*800 + k);
      acc[f] += v.x*wv.x + v.y*wv.y + v.z*wv.z + v.w*wv.w;
    }
  }
  const int lane = tid & 63, wid = tid >> 6;
  #pragma unroll
  for (int f = 0; f < 10; ++f) {
    acc[f] += __shfl_down(acc[f], 4);
    acc[f] += __shfl_down(acc[f], 2);
    acc[f] += __shfl_down(acc[f], 1);
    float a2 = (kc == 0) ? acc[f] : 0.f;
    float q2 = (kc == 0) ? acc[f]*acc[f] : 0.f;
    if (kc == 0) h_raw[(size_t)sample*10 + f] = acc[f];
    a2 += __shfl_down(a2, 32); q2 += __shfl_down(q2, 32);
    a2 += __shfl_down(a2, 16); q2 += __shfl_down(q2, 16);
    a2 += __shfl_down(a2, 8);  q2 += __shfl_down(q2, 8);
    if (lane == 0) { red[wid][f] = a2; red[wid][10+f] = q2; }
  }
  __syncthreads();
  if (tid < 20) {
    float t = 0.f;
    #pragma unroll
    for (int w2 = 0; w2 < 4; ++w2) t += red[w2][tid];
    part[(size_t)blockIdx.x*20 + tid] = t;
  }
}

// ---- BN3+ReLU, theta logits -> sigmoid, tree walk -> mu (32 samples/blk) ----
__global__ __launch_bounds__(256) void k_theta_mu(
    const float* __restrict__ h_raw, const float* __restrict__ bn3,
    const float* __restrict__ tw, const float* __restrict__ tb,
    float* __restrict__ mu)
{
  __shared__ float twt[10][256];
  __shared__ float tbl[256];
  __shared__ float hl[32][10];
  __shared__ float pl[32][256];
  const int tid = threadIdx.x, blk = blockIdx.x;
  for (int i = tid; i < 2550; i += 256) {
    const int node = i / 10, f = i - node*10;
    twt[f][node] = tw[i];
  }
  if (tid < 10) twt[tid][255] = 0.f;
  tbl[tid] = (tid < 255) ? tb[tid] : 0.f;
  for (int i = tid; i < 320; i += 256) {
    const int ss = i / 10, f = i - ss*10;
    hl[ss][f] = relu_(h_raw[(size_t)blk*320 + i] * bn3[f] + bn3[10 + f]);
  }
  __syncthreads();
  const int node = tid;
  for (int i2 = 0; i2 < 32; ++i2) {
    float h[10];
    #pragma unroll
    for (int f = 0; f < 10; ++f) h[f] = hl[i2][f];
    float d = tbl[node];
    #pragma unroll
    for (int f = 0; f < 10; ++f) d += h[f] * twt[f][node];
    pl[i2][node] = (node < 255) ? 1.f / (1.f + __expf(-d)) : 0.f;
  }
  __syncthreads();
  for (int i2 = 0; i2 < 32; ++i2) {
    float m = 1.f; int idx = 0;
    #pragma unroll
    for (int k = 0; k < 8; ++k) {
      const int dir = (tid >> (7 - k)) & 1;
      const float pv = pl[i2][idx];
      m *= dir ? pv : (1.f - pv);
      idx += dir ? (1 << (7 - k)) : 1;
    }
    mu[(size_t)(blk*32 + i2)*256 + tid] = m;
  }
}

// ---- S_raw[l,c] = sum over samples of class c of mu[b,l] ----
__global__ __launch_bounds__(256) void k_S(
    const float* __restrict__ mu, const int* __restrict__ y,
    float* __restrict__ S)
{
  const int tid = threadIdx.x;
  const int b0 = blockIdx.x * 16;
  float acc[10];
  #pragma unroll
  for (int c = 0; c < 10; ++c) acc[c] = 0.f;
  for (int s = 0; s < 16; ++s) {
    const int b = b0 + s;
    const float m = mu[(size_t)b*256 + tid];
    const int c = y[b];
    #pragma unroll
    for (int cc = 0; cc < 10; ++cc) acc[cc] += (c == cc) ? m : 0.f;
  }
  #pragma unroll
  for (int cc = 0; cc < 10; ++cc) atomicAdd(&S[tid*10 + cc], acc[cc]);
}

// ---- pi EM update (tiny, one block; thread = leaf) ----
__global__ __launch_bounds__(256) void k_pi(
    const float* __restrict__ pi, const float* __restrict__ S,
    float* __restrict__ pi_new)
{
  __shared__ float pin[2560];
  __shared__ float Pp[10];
  const int t = threadIdx.x;
  float row[10]; float rs = 0.f;
  #pragma unroll
  for (int c = 0; c < 10; ++c) { row[c] = pi[t*10 + c]; rs += row[c]; }
  #pragma unroll
  for (int c = 0; c < 10; ++c) { row[c] /= rs; pin[t*10 + c] = row[c]; }
  __syncthreads();
  if (t < 10) {
    float s = 0.f;
    for (int l = 0; l < 256; ++l) s += pin[l*10 + t];
    Pp[t] = s / 256.f;
  }
  __syncthreads();
  float hs = 0.f; float ph[10];
  #pragma unroll
  for (int c = 0; c < 10; ++c) {
    const float Sv = S[t*10 + c] / Pp[c];
    ph[c] = row[c] * Sv;
    hs += ph[c];
  }
  #pragma unroll
  for (int c = 0; c < 10; ++c) pi_new[t*10 + c] = ph[c] / hs;
}

// ---- out = log(mu @ pi_new), transposed+padded pi in LDS, float4 dot ----
__global__ __launch_bounds__(256) void k_out(
    const float* __restrict__ mu, const float* __restrict__ pn,
    float* __restrict__ out)
{
  __shared__ float plt[10][260];                // pad 260: breaks bank aliasing
  const int tid = threadIdx.x;
  if (tid < 256) {
    #pragma unroll
    for (int c = 0; c < 10; ++c) plt[c][tid] = pn[tid*10 + c];
  }
  __syncthreads();
  const int gid = blockIdx.x * 256 + tid;       // 81920 total
  const int b = gid / 10, c = gid % 10;
  const float4* mr4 = (const float4*)(mu + (size_t)b * 256);
  const float*  pc  = &plt[c][0];
  float a0 = 0.f, a1 = 0.f;
  #pragma unroll 4
  for (int l4 = 0; l4 < 64; ++l4) {
    const float4 m = mr4[l4];
    const float4 p = *(const float4*)(pc + 4*l4);
    a0 += m.x*p.x + m.y*p.y;
    a1 += m.z*p.z + m.w*p.w;
  }
  out[gid] = logf(a0 + a1);
}

extern "C" void kernel_launch(void* const* d_in, const int* in_sizes, int n_in,
                              void* d_out, int out_size, void* d_ws, size_t ws_size,
                              hipStream_t stream)
{
  const float* x   = (const float*)d_in[0];
  const int*   y   = (const int*)  d_in[1];
  const float* c1w = (const float*)d_in[2];
  const float* c2w = (const float*)d_in[4];
  const float* g1  = (const float*)d_in[6];
  const float* be1 = (const float*)d_in[7];
  const float* g2  = (const float*)d_in[8];
  const float* be2 = (const float*)d_in[9];
  const float* fw  = (const float*)d_in[10];
  const float* g3  = (const float*)d_in[12];
  const float* be3 = (const float*)d_in[13];
  const float* thw = (const float*)d_in[14];
  const float* thb = (const float*)d_in[15];
  const float* pi  = (const float*)d_in[16];
  float* ws  = (float*)d_ws;
  float* out = (float*)d_out;

  unsigned int*   rawp1b = (unsigned int*)(ws + F_RAWP1B);
  float*          c2p    = ws + F_C2P;
  float*          part1  = ws + F_PART1;
  float*          part2  = ws + F_PART2;
  float*          part3  = ws + F_PART3;
  float*          bn1    = ws + F_BN1;
  float*          bn2    = ws + F_BN2;
  float*          bn3    = ws + F_BN3;
  float*          sraw   = ws + F_SRAW;
  float*          pinew  = ws + F_PINEW;
  unsigned short* wb2    = (unsigned short*)(ws + F_WB2);
  unsigned short* wb1    = (unsigned short*)(ws + F_WB1);
  float*          hraw   = ws + F_HRAW;   // overlays rawp1b (dead after conv2)
  float*          muB    = ws + F_MU;

  hipMemsetAsync(sraw, 0, 2560 * sizeof(float), stream);

  k_wprep1<<<4, 256, 0, stream>>>(c1w, wb1);
  k_wprep2<<<152, 256, 0, stream>>>(c2w, wb2);
  k_conv1_mfma<<<8192, 256, 0, stream>>>(x, wb1, g1, rawp1b, part1);
  k_bn_fin<<<20, 256, 0, stream>>>(part1, 8192, 20, 8192.f * 576.f, g1, be1, bn1);
  k_conv2_mfma<<<2048, 256, 0, stream>>>(rawp1b, wb2, bn1, g2, c2p, part2);
  k_bn_fin<<<50, 256, 0, stream>>>(part2, 2048, 50, 8192.f * 64.f, g2, be2, bn2);
  k_fc1<<<256, 256, 0, stream>>>(c2p, bn2, fw, hraw, part3);
  k_bn_fin<<<10, 256, 0, stream>>>(part3, 256, 10, 8192.f, g3, be3, bn3);
  k_theta_mu<<<256, 256, 0, stream>>>(hraw, bn3, thw, thb, muB);
  k_S<<<512, 256, 0, stream>>>(muB, y, sraw);
  k_pi<<<1, 256, 0, stream>>>(pi, sraw, pinew);
  k_out<<<320, 256, 0, stream>>>(muB, pinew, out);
}

// Round 8
// 187.409 us; speedup vs baseline: 1.6562x; 1.6562x over previous
//
#include <hip/hip_runtime.h>
#include <hip/hip_bf16.h>
#include <math.h>

typedef __attribute__((ext_vector_type(8))) short short8v;
typedef __attribute__((ext_vector_type(4))) float float4v;

// ---------------- workspace layout (dword offsets) ----------------
static const size_t F_RAWP1B = 0;              // bf16 ch-last pooled raw conv1 [8192][144][12dw] = 14,155,776
static const size_t F_C2P    = 14155776;       // fp32 pooled raw conv2 [8192][800] = 6,553,600
static const size_t F_PART1  = 20709376;       // 8192*40
static const size_t F_PART2  = 21037056;       // 2048*100
static const size_t F_PART3  = 21241856;       // 256*20
static const size_t F_BN1    = 21246976;       // 40
static const size_t F_BN2    = 21247016;       // 100
static const size_t F_BN3    = 21247116;       // 20
static const size_t F_SRAW   = 21247136;       // 2560
static const size_t F_PINEW  = 21249696;       // 2560
static const size_t F_WB2    = 21252256;       // 19456 (76*64*8 bf16)
static const size_t F_WB1    = 21271712;       // 512   (32*32 bf16)
static const size_t F_SPART  = 21272224;       // 256*2560 = 655,360
// overlays in rawp1b region (dead after conv2):
static const size_t F_HRAW   = 0;              // 8192*10
static const size_t F_MU     = 81920;          // 8192*256

__device__ __forceinline__ float relu_(float v) { return v > 0.f ? v : 0.f; }

__device__ __forceinline__ unsigned int pack_bf16x2(float a, float b) {
  __hip_bfloat16 ha = __float2bfloat16(a), hb = __float2bfloat16(b);
  unsigned short ua, ub;
  __builtin_memcpy(&ua, &ha, 2); __builtin_memcpy(&ub, &hb, 2);
  return ((unsigned int)ub << 16) | ua;
}

__device__ __forceinline__ float pick_(float a, float b, bool mx) {
  return mx ? fmaxf(a, b) : fminf(a, b);
}

// ---- conv1 weight prep: (20,1,5,5) -> wb1[n(32)][k(32)] bf16, k = kh*6+kw ----
__global__ __launch_bounds__(256) void k_wprep1(
    const float* __restrict__ w, unsigned short* __restrict__ wb1)
{
  const int i = blockIdx.x * 256 + threadIdx.x;   // 1024
  const int n = i >> 5, k = i & 31;
  const int kh = k / 6, kw = k - kh*6;
  float v = (n < 20 && kh < 5 && kw < 5) ? w[n*25 + kh*5 + kw] : 0.f;
  __hip_bfloat16 h = __float2bfloat16(v);
  unsigned short u; __builtin_memcpy(&u, &h, 2);
  wb1[i] = u;
}

// ---- conv2 weight prep: OIHW fp32 -> wb2[cc(76)][n(64)][j(8)] bf16 ----
__global__ __launch_bounds__(256) void k_wprep2(
    const float* __restrict__ w, unsigned short* __restrict__ wb)
{
  const int idx = blockIdx.x * 256 + threadIdx.x;    // 38912
  const int cc = idx >> 9;
  const int rem = idx & 511;
  const int n = rem >> 3, j = rem & 7;
  float v = 0.f;
  if (cc < 75 && n < 50) {
    const int khw = cc / 3, icg = cc - khw*3;
    const int ic = icg*8 + j;
    if (ic < 20) {
      const int kh = khw / 5, kw = khw - kh*5;
      v = w[((n*20 + ic)*5 + kh)*5 + kw];
    }
  }
  __hip_bfloat16 h = __float2bfloat16(v);
  unsigned short u; __builtin_memcpy(&u, &h, 2);
  wb[idx] = u;
}

// ---- conv1 MFMA implicit GEMM, packed-pair dual-copy LDS gather ----
// k-map: k = kh*6+kw. Pixel mapping verified R5/R6. In-lane 2x2 pool.
// Output: bf16 packed ch-last pooled raw [img][144][12dw] (48 B/pixel).
__global__ __launch_bounds__(256) void k_conv1_mfma(
    const float* __restrict__ x, const unsigned short* __restrict__ wb1,
    const float* __restrict__ g1, unsigned int* __restrict__ rawp1b,
    float* __restrict__ part)
{
  __shared__ alignas(16) unsigned short xpk[1568];   // [2 copies][28 rows][28 ushort]
  __shared__ float sred[4][32], qred[4][32];
  const int tid = threadIdx.x, img = blockIdx.x;
  const float* xp = x + (size_t)img * 784;
  for (int i = tid; i < 784; i += 256) {
    const int r = i / 28, c = i - r*28;
    __hip_bfloat16 h = __float2bfloat16(xp[i]);
    unsigned short u; __builtin_memcpy(&u, &h, 2);
    xpk[r*28 + c] = u;                         // copy0: pair cols (2d, 2d+1)
    if (c >= 1) xpk[784 + r*28 + (c-1)] = u;   // copy1: pair cols (1+2d, 2+2d)
    else        xpk[784 + r*28 + 27]  = 0;     // copy1 col-28 slot = 0
  }
  __syncthreads();
  const int wave = tid >> 6, lane = tid & 63, lo = lane & 15, hi = lane >> 4;

  const short8v bfr0 = *(const short8v*)(wb1 + (lo*32 + hi*8));
  const short8v bfr1 = *(const short8v*)(wb1 + ((16+lo)*32 + hi*8));

  // per-hi dword offsets (kh*14 + kw/2) for jj=0..3, byte-encoded
  const unsigned enc = (hi==0) ? 0x0E020100u
                     : (hi==1) ? 0x1D1C100Fu
                     : (hi==2) ? 0x2C2B2A1Eu
                     :           0x003A3938u;   // hi=3: jj3 = zero-weight dummy
  const int off0 = enc & 255, off1 = (enc>>8)&255, off2 = (enc>>16)&255, off3 = enc>>24;
  const unsigned int* xpd = (const unsigned int*)xpk;   // 784 dwords
  const int pb   = (lo & 1) * 392;
  const int oyp  = (lo >> 1) & 1, qoff = lo >> 2;
  const int inv  = pb + (6*wave + oyp)*14;

  float4v acc[9][2];
  #pragma unroll
  for (int t = 0; t < 9; ++t) {
    acc[t][0] = (float4v){0.f,0.f,0.f,0.f};
    acc[t][1] = (float4v){0.f,0.f,0.f,0.f};
  }

  #pragma unroll
  for (int tt = 0; tt < 9; ++tt) {
    // qoff<=3 never crosses a 12-pixel row: pyl/pxl are compile-time
    const int pylc = (tt*4) / 12;
    const int pxlc = (tt*4) - pylc*12;
    const int base = inv + pylc*28 + pxlc + qoff;
    union { unsigned int u[4]; short8v v; } cu;
    cu.u[0] = xpd[base + off0];
    cu.u[1] = xpd[base + off1];
    cu.u[2] = xpd[base + off2];
    cu.u[3] = xpd[base + off3];
    acc[tt][0] = __builtin_amdgcn_mfma_f32_16x16x32_bf16(cu.v, bfr0, acc[tt][0], 0, 0, 0);
    acc[tt][1] = __builtin_amdgcn_mfma_f32_16x16x32_bf16(cu.v, bfr1, acc[tt][1], 0, 0, 0);
  }

  // epilogue: stats (pre-pool) + in-lane sign-aware 2x2 pool + bf16 pack store
  const bool gp0 = (g1[lo] >= 0.f);
  const bool gp1 = (lo < 4) ? (g1[16+lo] >= 0.f) : true;
  float sv0 = 0.f, qv0 = 0.f, sv1 = 0.f, qv1 = 0.f;
  unsigned int* dst = rawp1b + (size_t)img * 1728;
  #pragma unroll
  for (int tt = 0; tt < 9; ++tt) {
    const int T = wave*9 + tt;
    const int q = T*4 + hi;
    const float4v v0 = acc[tt][0];
    const float4v v1 = acc[tt][1];
    #pragma unroll
    for (int r = 0; r < 4; ++r) { sv0 += v0[r]; qv0 += v0[r]*v0[r]; }
    #pragma unroll
    for (int r = 0; r < 4; ++r) { sv1 += v1[r]; qv1 += v1[r]*v1[r]; }
    const float p0 = pick_(pick_(v0[0], v0[1], gp0), pick_(v0[2], v0[3], gp0), gp0);
    const float p1 = pick_(pick_(v1[0], v1[1], gp1), pick_(v1[2], v1[3], gp1), gp1);
    const float o0 = __shfl_down(p0, 1);
    const float o1 = __shfl_down(p1, 1);
    if ((lo & 1) == 0) {
      dst[q*12 + (lo >> 1)] = pack_bf16x2(p0, o0);          // oc pair (lo, lo+1)
      if (lo < 8)
        dst[q*12 + 8 + (lo >> 1)] = pack_bf16x2(p1, o1);    // oc 16.. (pads=0)
    }
  }
  sv0 += __shfl_down(sv0, 32); qv0 += __shfl_down(qv0, 32);
  sv0 += __shfl_down(sv0, 16); qv0 += __shfl_down(qv0, 16);
  sv1 += __shfl_down(sv1, 32); qv1 += __shfl_down(qv1, 32);
  sv1 += __shfl_down(sv1, 16); qv1 += __shfl_down(qv1, 16);
  if (hi == 0) {
    sred[wave][lo] = sv0; sred[wave][16+lo] = sv1;
    qred[wave][lo] = qv0; qred[wave][16+lo] = qv1;
  }
  __syncthreads();
  if (tid < 20) {
    float s = 0.f, q = 0.f;
    #pragma unroll
    for (int w2 = 0; w2 < 4; ++w2) { s += sred[w2][tid]; q += qred[w2][tid]; }
    part[(size_t)img*40 + tid]      = s;
    part[(size_t)img*40 + 20 + tid] = q;
  }
}

// ---- conv2 implicit-GEMM MFMA, unrolled K-loop + LDS A-offset table;
//      uint4 staging applies BN1+ReLU via interleaved (sc,sh) table;
//      epilogue: BN2 partial stats + in-register sign-aware 2x2 pool ----
__global__ __launch_bounds__(256) void k_conv2_mfma(
    const unsigned int* __restrict__ rawp1b, const unsigned short* __restrict__ wb,
    const float* __restrict__ bn1, const float* __restrict__ g2,
    float* __restrict__ c2p, float* __restrict__ part)
{
  __shared__ alignas(16) unsigned int in4[6912];     // 4 imgs, bf16 ch-last [144][12dw]
  __shared__ float sred[4][64], qred[4][64];
  __shared__ alignas(16) float bn1i[48];             // (sc,sh) interleaved, ch 0..23
  __shared__ unsigned short aofft[76];               // A byte-offset per K-chunk
  const int tid = threadIdx.x, blk = blockIdx.x;
  if (tid < 24) {
    const float sc = (tid < 20) ? bn1[tid]      : 0.f;
    const float sh = (tid < 20) ? bn1[20 + tid] : 0.f;
    bn1i[2*tid] = sc; bn1i[2*tid + 1] = sh;
  }
  if (tid < 76) {
    const int cc2 = tid > 74 ? 74 : tid;             // chunk 75: weights are 0
    const int khw = cc2 / 3, icg = cc2 - khw*3;
    const int kh = khw / 5, kw = khw - kh*5;
    aofft[tid] = (unsigned short)((kh*12 + kw)*48 + icg*16);
  }
  __syncthreads();

  // staging: 1728 uint4, unpack bf16 pair -> BN1+ReLU -> repack
  const uint4* src4 = (const uint4*)(rawp1b + (size_t)blk * 6912);
  uint4* dst4 = (uint4*)in4;
  int jj = tid % 3;                                  // dword chp base = jj*4
  for (int k = 0; k < 7; ++k) {
    const int i = k*256 + tid;
    if (i < 1728) {
      const uint4 v = src4[i];
      unsigned int o[4];
      #pragma unroll
      for (int m = 0; m < 4; ++m) {
        const float4 ss = *(const float4*)(bn1i + jj*16 + m*4);
        const unsigned int u = (m==0) ? v.x : (m==1) ? v.y : (m==2) ? v.z : v.w;
        const float a = __uint_as_float(u << 16);
        const float b = __uint_as_float(u & 0xffff0000u);
        const float ra = relu_(fmaf(a, ss.x, ss.y));
        const float rb = relu_(fmaf(b, ss.z, ss.w));
        o[m] = pack_bf16x2(ra, rb);
      }
      uint4 ov; ov.x = o[0]; ov.y = o[1]; ov.z = o[2]; ov.w = o[3];
      dst4[i] = ov;
    }
    jj = (jj == 2) ? 0 : jj + 1;                     // 256 % 3 == 1
  }
  __syncthreads();

  const int wave = tid >> 6, lane = tid & 63;
  const int lo = lane & 15, hi = lane >> 4;
  const char* ibase = (const char*)in4 + wave * 6912;

  // per-lane A bases (pixel*48 bytes) and per-step A offsets from table
  const char* bA[4];
  #pragma unroll
  for (int a = 0; a < 4; ++a) {
    const int m = a*16 + lo;
    bA[a] = ibase + ((m >> 3) * 12 + (m & 7)) * 48;
  }
  unsigned short aoffs[19];
  #pragma unroll
  for (int s = 0; s < 19; ++s) aoffs[s] = aofft[s*4 + hi];
  const unsigned short* wbase = wb + hi*512 + lo*8;

  bool gpos[4];
  #pragma unroll
  for (int nf = 0; nf < 4; ++nf) {
    const int n = nf*16 + lo;
    gpos[nf] = (n < 50) ? (g2[n] >= 0.f) : true;
  }

  float4v acc[4][4];
  #pragma unroll
  for (int a = 0; a < 4; ++a)
    #pragma unroll
    for (int nf = 0; nf < 4; ++nf) acc[a][nf] = (float4v){0.f, 0.f, 0.f, 0.f};

  #pragma unroll
  for (int s = 0; s < 19; ++s) {
    short8v av[4], bv[4];
    #pragma unroll
    for (int am = 0; am < 4; ++am)
      av[am] = *(const short8v*)(bA[am] + aoffs[s]);
    const unsigned short* wrow = wbase + s*2048;     // (4s+hi)*512 + lo*8
    #pragma unroll
    for (int nf = 0; nf < 4; ++nf)
      bv[nf] = *(const short8v*)(wrow + nf*128);
    #pragma unroll
    for (int am = 0; am < 4; ++am)
      #pragma unroll
      for (int nf = 0; nf < 4; ++nf)
        acc[am][nf] = __builtin_amdgcn_mfma_f32_16x16x32_bf16(av[am], bv[nf], acc[am][nf], 0, 0, 0);
  }

  const int img = blk*4 + wave;
  #pragma unroll
  for (int nf = 0; nf < 4; ++nf) {
    const int n = nf*16 + lo;
    float sv = 0.f, qv = 0.f;
    #pragma unroll
    for (int am = 0; am < 4; ++am) {
      float4v v = acc[am][nf];
      #pragma unroll
      for (int r = 0; r < 4; ++r) { sv += v[r]; qv += v[r]*v[r]; }
      float h0 = gpos[nf] ? fmaxf(v[0], v[1]) : fminf(v[0], v[1]);
      float h1 = gpos[nf] ? fmaxf(v[2], v[3]) : fminf(v[2], v[3]);
      const float o0 = __shfl_xor(h0, 32);
      const float o1 = __shfl_xor(h1, 32);
      h0 = gpos[nf] ? fmaxf(h0, o0) : fminf(h0, o0);
      h1 = gpos[nf] ? fmaxf(h1, o1) : fminf(h1, o1);
      if (hi < 2 && n < 50) {
        float2 o; o.x = h0; o.y = h1;
        *(float2*)(c2p + (size_t)img*800 + n*16 + am*4 + hi*2) = o;
      }
    }
    sv += __shfl_down(sv, 32); qv += __shfl_down(qv, 32);
    sv += __shfl_down(sv, 16); qv += __shfl_down(qv, 16);
    if (hi == 0) { sred[wave][nf*16 + lo] = sv; qred[wave][nf*16 + lo] = qv; }
  }
  __syncthreads();
  if (tid < 100) {
    const int ch = tid < 50 ? tid : tid - 50;
    float t = 0.f;
    if (tid < 50) {
      #pragma unroll
      for (int w2 = 0; w2 < 4; ++w2) t += sred[w2][ch];
      part[(size_t)blk*100 + ch] = t;
    } else {
      #pragma unroll
      for (int w2 = 0; w2 < 4; ++w2) t += qred[w2][ch];
      part[(size_t)blk*100 + 50 + ch] = t;
    }
  }
}

// ---- BN finalize: reduce per-block partials (double), emit scale/shift ----
__global__ __launch_bounds__(256) void k_bn_fin(
    const float* __restrict__ part, int nblk, int nch, float N,
    const float* __restrict__ g, const float* __restrict__ b,
    float* __restrict__ out)
{
  __shared__ double rd[4][2];
  const int tid = threadIdx.x, ch = blockIdx.x;
  const int lane = tid & 63, wid = tid >> 6;
  double s = 0.0, q = 0.0;
  for (int i = tid; i < nblk; i += 256) {
    s += (double)part[(size_t)i*2*nch + ch];
    q += (double)part[(size_t)i*2*nch + nch + ch];
  }
  #pragma unroll
  for (int off = 32; off > 0; off >>= 1) { s += __shfl_down(s, off); q += __shfl_down(q, off); }
  if (lane == 0) { rd[wid][0] = s; rd[wid][1] = q; }
  __syncthreads();
  if (tid == 0) {
    double S = rd[0][0] + rd[1][0] + rd[2][0] + rd[3][0];
    double Q = rd[0][1] + rd[1][1] + rd[2][1] + rd[3][1];
    double mean = S / (double)N;
    double var  = Q / (double)N - mean * mean;
    if (var < 0.0) var = 0.0;
    float scv = (float)((double)g[ch] / sqrt(var + 1e-5));
    out[ch]       = scv;
    out[nch + ch] = b[ch] - (float)mean * scv;
  }
}

// ---- fc1 fused BN2+ReLU: 32 samples/block, 8-lane K-split ----
__global__ __launch_bounds__(256) void k_fc1(
    const float* __restrict__ c2p, const float* __restrict__ bn2,
    const float* __restrict__ fw, float* __restrict__ h_raw,
    float* __restrict__ part)
{
  __shared__ alignas(16) float wl[8000];
  __shared__ float s2[50], h2[50];
  __shared__ float red[4][20];
  const int tid = threadIdx.x;
  for (int i = tid; i < 2000; i += 256)
    ((float4*)wl)[i] = ((const float4*)fw)[i];
  if (tid < 50) { s2[tid] = bn2[tid]; h2[tid] = bn2[50 + tid]; }
  __syncthreads();
  const int s = tid >> 3, kc = tid & 7;
  const int sample = blockIdx.x * 32 + s;
  const float* xr = c2p + (size_t)sample * 800 + kc * 100;
  float acc[10];
  #pragma unroll
  for (int f = 0; f < 10; ++f) acc[f] = 0.f;
  #pragma unroll 5
  for (int c = 0; c < 25; ++c) {
    const int k = kc*100 + c*4;
    float4 v = *(const float4*)(xr + c*4);
    const int oc = k >> 4;
    const float sc = s2[oc], sh = h2[oc];
    v.x = relu_(v.x*sc + sh); v.y = relu_(v.y*sc + sh);
    v.z = relu_(v.z*sc + sh); v.w = relu_(v.w*sc + sh);
    #pragma unroll
    for (int f = 0; f < 10; ++f) {
      const float4 wv = *(const float4*)(wl + f*800 + k);
      acc[f] += v.x*wv.x + v.y*wv.y + v.z*wv.z + v.w*wv.w;
    }
  }
  const int lane = tid & 63, wid = tid >> 6;
  #pragma unroll
  for (int f = 0; f < 10; ++f) {
    acc[f] += __shfl_down(acc[f], 4);
    acc[f] += __shfl_down(acc[f], 2);
    acc[f] += __shfl_down(acc[f], 1);
    float a2 = (kc == 0) ? acc[f] : 0.f;
    float q2 = (kc == 0) ? acc[f]*acc[f] : 0.f;
    if (kc == 0) h_raw[(size_t)sample*10 + f] = acc[f];
    a2 += __shfl_down(a2, 32); q2 += __shfl_down(q2, 32);
    a2 += __shfl_down(a2, 16); q2 += __shfl_down(q2, 16);
    a2 += __shfl_down(a2, 8);  q2 += __shfl_down(q2, 8);
    if (lane == 0) { red[wid][f] = a2; red[wid][10+f] = q2; }
  }
  __syncthreads();
  if (tid < 20) {
    float t = 0.f;
    #pragma unroll
    for (int w2 = 0; w2 < 4; ++w2) t += red[w2][tid];
    part[(size_t)blockIdx.x*20 + tid] = t;
  }
}

// ---- BN3+ReLU, theta logits -> sigmoid, tree walk -> mu (32 samples/blk) ----
__global__ __launch_bounds__(256) void k_theta_mu(
    const float* __restrict__ h_raw, const float* __restrict__ bn3,
    const float* __restrict__ tw, const float* __restrict__ tb,
    float* __restrict__ mu)
{
  __shared__ float twt[10][256];
  __shared__ float tbl[256];
  __shared__ float hl[32][10];
  __shared__ float pl[32][256];
  const int tid = threadIdx.x, blk = blockIdx.x;
  for (int i = tid; i < 2550; i += 256) {
    const int node = i / 10, f = i - node*10;
    twt[f][node] = tw[i];
  }
  if (tid < 10) twt[tid][255] = 0.f;
  tbl[tid] = (tid < 255) ? tb[tid] : 0.f;
  for (int i = tid; i < 320; i += 256) {
    const int ss = i / 10, f = i - ss*10;
    hl[ss][f] = relu_(h_raw[(size_t)blk*320 + i] * bn3[f] + bn3[10 + f]);
  }
  __syncthreads();
  const int node = tid;
  for (int i2 = 0; i2 < 32; ++i2) {
    float h[10];
    #pragma unroll
    for (int f = 0; f < 10; ++f) h[f] = hl[i2][f];
    float d = tbl[node];
    #pragma unroll
    for (int f = 0; f < 10; ++f) d += h[f] * twt[f][node];
    pl[i2][node] = (node < 255) ? 1.f / (1.f + __expf(-d)) : 0.f;
  }
  __syncthreads();
  for (int i2 = 0; i2 < 32; ++i2) {
    float m = 1.f; int idx = 0;
    #pragma unroll
    for (int k = 0; k < 8; ++k) {
      const int dir = (tid >> (7 - k)) & 1;
      const float pv = pl[i2][idx];
      m *= dir ? pv : (1.f - pv);
      idx += dir ? (1 << (7 - k)) : 1;
    }
    mu[(size_t)(blk*32 + i2)*256 + tid] = m;
  }
}

// ---- S stage A: per-block partial S[leaf][class] over 32 samples, no atomics ----
__global__ __launch_bounds__(256) void k_S_part(
    const float* __restrict__ mu, const int* __restrict__ y,
    float* __restrict__ spart)
{
  const int tid = threadIdx.x;          // = leaf
  const int b0 = blockIdx.x * 32;
  float acc[10];
  #pragma unroll
  for (int c = 0; c < 10; ++c) acc[c] = 0.f;
  for (int s = 0; s < 32; ++s) {
    const int b = b0 + s;
    const float m = mu[(size_t)b*256 + tid];
    const int c = y[b];                 // wave-uniform -> scalar load
    #pragma unroll
    for (int cc = 0; cc < 10; ++cc) acc[cc] += (c == cc) ? m : 0.f;
  }
  float* dst = spart + (size_t)blockIdx.x*2560 + tid*10;
  #pragma unroll
  for (int cc = 0; cc < 10; ++cc) dst[cc] = acc[cc];
}

// ---- S stage B: reduce 256 partials -> S[2560] ----
__global__ __launch_bounds__(256) void k_S_red(
    const float* __restrict__ spart, float* __restrict__ S)
{
  const int e = blockIdx.x * 256 + threadIdx.x;   // 2560
  float s = 0.f;
  for (int k = 0; k < 256; ++k) s += spart[(size_t)k*2560 + e];
  S[e] = s;
}

// ---- pi EM update (tiny, one block; thread = leaf) ----
__global__ __launch_bounds__(256) void k_pi(
    const float* __restrict__ pi, const float* __restrict__ S,
    float* __restrict__ pi_new)
{
  __shared__ float pin[2560];
  __shared__ float Pp[10];
  const int t = threadIdx.x;
  float row[10]; float rs = 0.f;
  #pragma unroll
  for (int c = 0; c < 10; ++c) { row[c] = pi[t*10 + c]; rs += row[c]; }
  #pragma unroll
  for (int c = 0; c < 10; ++c) { row[c] /= rs; pin[t*10 + c] = row[c]; }
  __syncthreads();
  if (t < 10) {
    float s = 0.f;
    for (int l = 0; l < 256; ++l) s += pin[l*10 + t];
    Pp[t] = s / 256.f;
  }
  __syncthreads();
  float hs = 0.f; float ph[10];
  #pragma unroll
  for (int c = 0; c < 10; ++c) {
    const float Sv = S[t*10 + c] / Pp[c];
    ph[c] = row[c] * Sv;
    hs += ph[c];
  }
  #pragma unroll
  for (int c = 0; c < 10; ++c) pi_new[t*10 + c] = ph[c] / hs;
}

// ---- out = log(mu @ pi_new), transposed+padded pi in LDS, float4 dot ----
__global__ __launch_bounds__(256) void k_out(
    const float* __restrict__ mu, const float* __restrict__ pn,
    float* __restrict__ out)
{
  __shared__ float plt[10][260];                // pad 260: breaks bank aliasing
  const int tid = threadIdx.x;
  if (tid < 256) {
    #pragma unroll
    for (int c = 0; c < 10; ++c) plt[c][tid] = pn[tid*10 + c];
  }
  __syncthreads();
  const int gid = blockIdx.x * 256 + tid;       // 81920 total
  const int b = gid / 10, c = gid % 10;
  const float4* mr4 = (const float4*)(mu + (size_t)b * 256);
  const float*  pc  = &plt[c][0];
  float a0 = 0.f, a1 = 0.f;
  #pragma unroll 4
  for (int l4 = 0; l4 < 64; ++l4) {
    const float4 m = mr4[l4];
    const float4 p = *(const float4*)(pc + 4*l4);
    a0 += m.x*p.x + m.y*p.y;
    a1 += m.z*p.z + m.w*p.w;
  }
  out[gid] = logf(a0 + a1);
}

extern "C" void kernel_launch(void* const* d_in, const int* in_sizes, int n_in,
                              void* d_out, int out_size, void* d_ws, size_t ws_size,
                              hipStream_t stream)
{
  const float* x   = (const float*)d_in[0];
  const int*   y   = (const int*)  d_in[1];
  const float* c1w = (const float*)d_in[2];
  const float* c2w = (const float*)d_in[4];
  const float* g1  = (const float*)d_in[6];
  const float* be1 = (const float*)d_in[7];
  const float* g2  = (const float*)d_in[8];
  const float* be2 = (const float*)d_in[9];
  const float* fw  = (const float*)d_in[10];
  const float* g3  = (const float*)d_in[12];
  const float* be3 = (const float*)d_in[13];
  const float* thw = (const float*)d_in[14];
  const float* thb = (const float*)d_in[15];
  const float* pi  = (const float*)d_in[16];
  float* ws  = (float*)d_ws;
  float* out = (float*)d_out;

  unsigned int*   rawp1b = (unsigned int*)(ws + F_RAWP1B);
  float*          c2p    = ws + F_C2P;
  float*          part1  = ws + F_PART1;
  float*          part2  = ws + F_PART2;
  float*          part3  = ws + F_PART3;
  float*          bn1    = ws + F_BN1;
  float*          bn2    = ws + F_BN2;
  float*          bn3    = ws + F_BN3;
  float*          sraw   = ws + F_SRAW;
  float*          pinew  = ws + F_PINEW;
  unsigned short* wb2    = (unsigned short*)(ws + F_WB2);
  unsigned short* wb1    = (unsigned short*)(ws + F_WB1);
  float*          spart  = ws + F_SPART;
  float*          hraw   = ws + F_HRAW;   // overlays rawp1b (dead after conv2)
  float*          muB    = ws + F_MU;

  k_wprep1<<<4, 256, 0, stream>>>(c1w, wb1);
  k_wprep2<<<152, 256, 0, stream>>>(c2w, wb2);
  k_conv1_mfma<<<8192, 256, 0, stream>>>(x, wb1, g1, rawp1b, part1);
  k_bn_fin<<<20, 256, 0, stream>>>(part1, 8192, 20, 8192.f * 576.f, g1, be1, bn1);
  k_conv2_mfma<<<2048, 256, 0, stream>>>(rawp1b, wb2, bn1, g2, c2p, part2);
  k_bn_fin<<<50, 256, 0, stream>>>(part2, 2048, 50, 8192.f * 64.f, g2, be2, bn2);
  k_fc1<<<256, 256, 0, stream>>>(c2p, bn2, fw, hraw, part3);
  k_bn_fin<<<10, 256, 0, stream>>>(part3, 256, 10, 8192.f, g3, be3, bn3);
  k_theta_mu<<<256, 256, 0, stream>>>(hraw, bn3, thw, thb, muB);
  k_S_part<<<256, 256, 0, stream>>>(muB, y, spart);
  k_S_red<<<10, 256, 0, stream>>>(spart, sraw);
  k_pi<<<1, 256, 0, stream>>>(pi, sraw, pinew);
  k_out<<<320, 256, 0, stream>>>(muB, pinew, out);
}